// Round 10
// baseline (13795.212 us; speedup 1.0000x reference)
//
#include <hip/hip_runtime.h>
#include <cstddef>
#include <cstdint>

namespace {

constexpr int kB  = 4096;   // batch
constexpr int kIN = 4096;
constexpr int kFS = 4096;
constexpr int kS  = 64;
constexpr int kH  = 512;
constexpr int kNG = 2048;   // 4*H
constexpr int kKC = 576;    // 64 (input slice) + 512 (hidden)
constexpr int kRowB = 1152; // LDS bytes per A-row: 576 bf16 = 72 x 16B slots

typedef __bf16 bf16_t;
typedef __bf16 bfrag  __attribute__((ext_vector_type(8)));
typedef __bf16 bf16v4 __attribute__((ext_vector_type(4)));
typedef float  f32x4  __attribute__((ext_vector_type(4)));

__device__ __forceinline__ void gload16(const void* g, void* l) {
  __builtin_amdgcn_global_load_lds(
      (const __attribute__((address_space(1))) void*)g,
      (__attribute__((address_space(3))) void*)l, 16, 0, 0);
}

__device__ __forceinline__ float sigf(float x) { return 1.0f / (1.0f + __expf(-x)); }
__device__ __forceinline__ float tanh_fast(float x) {
  float e = __expf(2.0f * x);
  return 1.0f - 2.0f / (e + 1.0f);
}
__device__ __forceinline__ f32x4 mfma16(bfrag a, bfrag b, f32x4 c) {
  return __builtin_amdgcn_mfma_f32_16x16x32_bf16(a, b, c, 0, 0, 0);
}
__device__ __forceinline__ unsigned short bf16bits(float v) {
  __bf16 b = (__bf16)v;
  return __builtin_bit_cast(unsigned short, b);
}

// ---------------- pack kernels ----------------

__global__ __launch_bounds__(256) void f2b4_kernel(const float* __restrict__ in,
                                                   bf16_t* __restrict__ out, int n4) {
  int i = blockIdx.x * 256 + threadIdx.x;
  if (i >= n4) return;
  float4 v = reinterpret_cast<const float4*>(in)[i];
  bf16v4 o = {(bf16_t)v.x, (bf16_t)v.y, (bf16_t)v.z, (bf16_t)v.w};
  *reinterpret_cast<bf16v4*>(out + (size_t)i * 4) = o;
}

// wcat2: MFMA-fragment-order weight pack (verified in R9).
// chunk (mat, nb, kt, kk) = 64 lanes x 8 bf16; lane l: col = nb*16+(l&15),
// k = kt*64 + kk*32 + (l>>4)*8. col c -> gate=(c>>4)&3, unit=(c>>6)*16+(c&15).
__global__ __launch_bounds__(256) void pack_wcat2_kernel(
    const float* __restrict__ Wih_l, const float* __restrict__ Whh_l,
    const float* __restrict__ Wih_r, const float* __restrict__ Whh_r,
    const float* __restrict__ Wih_d, const float* __restrict__ Whh_d,
    bf16_t* __restrict__ wcat2) {
  const int total = 3 * 128 * 9 * 2 * 64 * 8;
  int idx = blockIdx.x * 256 + threadIdx.x;
  if (idx >= total) return;
  int e  = idx & 7;
  int l  = (idx >> 3) & 63;
  int kk = (idx >> 9) & 1;
  int r  = idx >> 10;
  int kt = r % 9;
  int matnb = r / 9;
  int mat = matnb >> 7;
  int nb  = matnb & 127;
  const int c = nb * 16 + (l & 15);
  const int g = (c >> 4) & 3;
  const int u = (c >> 6) * 16 + (c & 15);
  const int orow = g * kH + u;
  const int k = kt * 64 + kk * 32 + (l >> 4) * 8 + e;
  const float* Wih = (mat == 0) ? Wih_l : (mat == 1) ? Wih_r : Wih_d;
  const float* Whh = (mat == 0) ? Whh_l : (mat == 1) ? Whh_r : Whh_d;
  float v = (k < 64) ? Wih[(size_t)orow * 64 + k] : Whh[(size_t)orow * 512 + (k - 64)];
  wcat2[idx] = (bf16_t)v;
}

__global__ __launch_bounds__(256) void pack_bias_kernel(
    const float* __restrict__ bih_l, const float* __restrict__ bhh_l,
    const float* __restrict__ bih_r, const float* __restrict__ bhh_r,
    const float* __restrict__ bih_d, const float* __restrict__ bhh_d,
    float* __restrict__ biasc) {
  int idx = blockIdx.x * 256 + threadIdx.x;
  if (idx >= 3 * kNG) return;
  int mat = idx / kNG;
  int c = idx - mat * kNG;
  int g = (c >> 4) & 3;
  int u = (c >> 6) * 16 + (c & 15);
  int orow = g * kH + u;
  const float* bi = (mat == 0) ? bih_l : (mat == 1) ? bih_r : bih_d;
  const float* bh = (mat == 0) ? bhh_l : (mat == 1) ? bhh_r : bhh_d;
  biasc[idx] = bi[orow] + bh[orow];
}

__global__ __launch_bounds__(256) void transpose64_kernel(const bf16_t* __restrict__ feat,
                                                          bf16_t* __restrict__ featT) {
  __shared__ bf16_t tile[64][65];
  const int b = blockIdx.x;
  const bf16_t* src = feat + (size_t)b * kFS;
  bf16_t* dst = featT + (size_t)b * kFS;
  for (int i = threadIdx.x; i < 4096; i += 256) tile[i >> 6][i & 63] = src[i];
  __syncthreads();
  for (int i = threadIdx.x; i < 4096; i += 256) dst[i] = tile[i & 63][i >> 6];
}

// ---------------- feat GEMM (unchanged, verified) ----------------

__global__ __launch_bounds__(256, 4) void gemm_feat_kernel(
    const bf16_t* __restrict__ X, const bf16_t* __restrict__ W,
    const float* __restrict__ b1, bf16_t* __restrict__ feat) {
  __shared__ bf16_t As[128 * 32];
  __shared__ bf16_t Bs[128 * 32];
  const int t = threadIdx.x;
  const int bid = blockIdx.x;
  const int widx = (bid & 7) * 128 + (bid >> 3);
  const int bm = widx & 31, bn = widx >> 5;
  const int w = t >> 6, l = t & 63;
  const int wm = (w >> 1) * 64, wn = (w & 1) * 64;
  const int sr = t >> 2;
  const int skS = ((t & 3) ^ ((t >> 3) & 3)) * 8;
  const int lr = l & 15;
  const int lkS = ((l >> 4) ^ ((l >> 1) & 3)) * 8;
  const int lrow4 = (l >> 4) * 4;

  f32x4 acc[4][4];
#pragma unroll
  for (int i = 0; i < 4; ++i)
#pragma unroll
    for (int j = 0; j < 4; ++j) acc[i][j] = (f32x4){0.f, 0.f, 0.f, 0.f};

  const bf16_t* ga = X + (size_t)(bm * 128 + sr) * kIN + skS;
  const bf16_t* gb = W + (size_t)(bn * 128 + sr) * kIN + skS;
  bf16_t* lA = As + w * 512;
  bf16_t* lB = Bs + w * 512;

  for (int kt = 0; kt < kIN / 32; ++kt) {
    gload16(ga, lA);
    gload16(ga + (size_t)64 * kIN, lA + 2048);
    gload16(gb, lB);
    gload16(gb + (size_t)64 * kIN, lB + 2048);
    ga += 32; gb += 32;
    __syncthreads();
    bfrag a[4], b[4];
#pragma unroll
    for (int mi = 0; mi < 4; ++mi)
      a[mi] = *reinterpret_cast<const bfrag*>(&As[(wm + mi * 16 + lr) * 32 + lkS]);
#pragma unroll
    for (int ni = 0; ni < 4; ++ni)
      b[ni] = *reinterpret_cast<const bfrag*>(&Bs[(wn + ni * 16 + lr) * 32 + lkS]);
#pragma unroll
    for (int mi = 0; mi < 4; ++mi)
#pragma unroll
      for (int ni = 0; ni < 4; ++ni)
        acc[mi][ni] = __builtin_amdgcn_mfma_f32_16x16x32_bf16(a[mi], b[ni], acc[mi][ni], 0, 0, 0);
    __syncthreads();
  }

#pragma unroll
  for (int ni = 0; ni < 4; ++ni) {
    const int col = bn * 128 + wn + ni * 16 + lr;
    const float bb = b1[col];
#pragma unroll
    for (int mi = 0; mi < 4; ++mi) {
#pragma unroll
      for (int r = 0; r < 4; ++r) {
        const int row = bm * 128 + wm + mi * 16 + lrow4 + r;
        float v = acc[mi][ni][r] + bb;
        feat[(size_t)row * kFS + col] = (bf16_t)fmaxf(v, 0.0f);
      }
    }
  }
}

// ---------------- fused all-64-steps LSTM kernel ----------------
// 256 independent blocks (4 cells x 64 row-blocks of 64 rows). Block owns its rows'
// ENTIRE recurrence: A[64][576] (x-slice | h) lives in LDS for all 64 steps (XOR
// swizzle slot^=row&7, conflict-free b128 reads per 16-lane phase); h never touches
// global until s=63. c is thread-private in a block-packed coalesced fp32 workspace.
// Per step: 4 N-chunks x 9 K-tiles, fully unrolled (static reg indices), B fragments
// streamed from wcat2 (1-ahead ping-pong prefetch incl. across the step boundary),
// zero K-loop barriers, 2 barriers/step (around h-writeback + x(s+1) stage).
// Cell<->XCD-pair mapping (cell=(bid&7)>>1) keeps each L2's weights at 2.36 MB.

__global__ __launch_bounds__(512, 1) void lstm_all_kernel(
    const bf16_t* __restrict__ feat, const bf16_t* __restrict__ featT,
    const bf16_t* __restrict__ wcat2, const float* __restrict__ biasc,
    const float* __restrict__ h0, const float* __restrict__ c0,
    float* __restrict__ cbuf, bf16_t* __restrict__ hfin) {
  extern __shared__ __align__(16) char smem[];   // 64 rows x 1152 B = 72 KB

  const int t = threadIdx.x;
  const int l = t & 63, w = t >> 6;          // 8 waves; wave w owns cols w*64.. per chunk
  const int lr = l & 15, lq = l >> 4;
  const int sx = lr & 7;
  const int e0 = lq ^ sx;                     // kk=0 swizzled low-slot
  const int e1 = (4 + lq) ^ sx;               // kk=1

  const int bid = blockIdx.x;
  const int cell = (bid & 7) >> 1;            // XCD-pair per cell (perf heuristic only)
  const int rb = ((bid & 7) & 1) * 32 + (bid >> 3);
  const int row0 = rb * 64;
  const int mat = (cell < 2) ? cell : 2;
  const bf16_t* xsrc = (cell < 2) ? feat : featT;

  // per-lane A-read base addresses (mi x kk), K-tile advances via +kt*128 bytes
  const char* aBase[4][2];
#pragma unroll
  for (int mi = 0; mi < 4; ++mi) {
    const int rowb = (mi * 16 + lr) * kRowB;
    aBase[mi][0] = smem + rowb + e0 * 16;
    aBase[mi][1] = smem + rowb + e1 * 16;
  }

  const size_t nbBase = (size_t)mat * 128 + w * 4;
  auto loadB = [&](int ch, int kt, bfrag (&d)[8]) {
#pragma unroll
    for (int nn = 0; nn < 4; ++nn)
#pragma unroll
      for (int kk = 0; kk < 2; ++kk)
        d[nn * 2 + kk] = *reinterpret_cast<const bfrag*>(
            wcat2 + ((((nbBase + ch * 32 + nn) * 9 + kt) * 2 + kk) << 9) + l * 8);
  };

  // ---- prologue: stage x(0) + init h region from h0 ----
  {
    const int xr = t >> 3, xs_ = t & 7;
    bfrag xv = *reinterpret_cast<const bfrag*>(
        xsrc + (size_t)(row0 + xr) * kFS + ((cell & 1) ? 63 : 0) * 64 + xs_ * 8);
    *reinterpret_cast<bfrag*>(smem + xr * kRowB + ((xs_ ^ (xr & 7)) * 16)) = xv;
    const int u0 = (t & 7) * 64;
    const float* hp = h0 + ((size_t)cell * kB + row0 + xr) * kH + u0;
#pragma unroll
    for (int i = 0; i < 8; ++i) {
      bfrag hv;
#pragma unroll
      for (int e = 0; e < 8; ++e) hv[e] = (bf16_t)hp[i * 8 + e];
      const int sl = (8 + (u0 >> 3) + i) ^ (xr & 7);
      *reinterpret_cast<bfrag*>(smem + xr * kRowB + sl * 16) = hv;
    }
  }
  __syncthreads();

  f32x4 acc[4][4];
#pragma unroll
  for (int i = 0; i < 4; ++i)
#pragma unroll
    for (int j = 0; j < 4; ++j) acc[i][j] = (f32x4){0.f, 0.f, 0.f, 0.f};

  bfrag bE[8], bO[8];
  unsigned hpk[4][8];
  loadB(0, 0, bE);

#pragma unroll 1
  for (int s = 0; s < 64; ++s) {
#pragma unroll
    for (int ch = 0; ch < 4; ++ch) {
#pragma unroll
      for (int kt = 0; kt < 9; ++kt) {
        const int i = ch * 9 + kt;
        bfrag (&bc)[8] = (i & 1) ? bO : bE;
        bfrag (&bn_)[8] = (i & 1) ? bE : bO;
        if (i < 35) loadB((i + 1) / 9, (i + 1) % 9, bn_);
        else        loadB(0, 0, bn_);   // prefetch next step's first chunk (same weights)
        bfrag a[8];
#pragma unroll
        for (int mi = 0; mi < 4; ++mi) {
          a[mi * 2 + 0] = *reinterpret_cast<const bfrag*>(aBase[mi][0] + kt * 128);
          a[mi * 2 + 1] = *reinterpret_cast<const bfrag*>(aBase[mi][1] + kt * 128);
        }
#pragma unroll
        for (int kk = 0; kk < 2; ++kk)
#pragma unroll
          for (int mi = 0; mi < 4; ++mi)
#pragma unroll
            for (int nn = 0; nn < 4; ++nn)
              acc[mi][nn] = mfma16(a[mi * 2 + kk], bc[nn * 2 + kk], acc[mi][nn]);
      }
      // ---- chunk epilogue: gates -> c update -> h (stash or final write) ----
      {
        const float* bbp = biasc + mat * kNG + ch * 512 + w * 64;
        const float bb0 = bbp[lr], bb1 = bbp[16 + lr], bb2 = bbp[32 + lr], bb3 = bbp[48 + lr];
        const int u = (ch * 8 + w) * 16 + lr;
        float* cp = cbuf + ((((size_t)bid * 4 + ch) * 8 + w) * 64 + l) * 16;
#pragma unroll
        for (int mi = 0; mi < 4; ++mi) {
          float cv[4];
          if (s == 0) {
            const float* c0p = c0 + ((size_t)cell * kB + row0 + mi * 16 + lq * 4) * kH + u;
#pragma unroll
            for (int j = 0; j < 4; ++j) cv[j] = c0p[(size_t)j * kH];
          } else {
            float4 c4 = reinterpret_cast<const float4*>(cp)[mi];
            cv[0] = c4.x; cv[1] = c4.y; cv[2] = c4.z; cv[3] = c4.w;
          }
          float hv[4];
#pragma unroll
          for (int j = 0; j < 4; ++j) {
            const float iv = sigf(acc[mi][0][j] + bb0);
            const float fv = sigf(acc[mi][1][j] + bb1);
            const float gv = tanh_fast(acc[mi][2][j] + bb2);
            const float ov = sigf(acc[mi][3][j] + bb3);
            const float cn = fv * cv[j] + iv * gv;
            cv[j] = cn;
            hv[j] = ov * tanh_fast(cn);
          }
          reinterpret_cast<float4*>(cp)[mi] = make_float4(cv[0], cv[1], cv[2], cv[3]);
          if (s < 63) {
            hpk[ch][mi * 2 + 0] = (unsigned)bf16bits(hv[0]) | ((unsigned)bf16bits(hv[1]) << 16);
            hpk[ch][mi * 2 + 1] = (unsigned)bf16bits(hv[2]) | ((unsigned)bf16bits(hv[3]) << 16);
          } else {
#pragma unroll
            for (int j = 0; j < 4; ++j)
              hfin[((size_t)cell * kB + row0 + mi * 16 + lq * 4 + j) * kH + u] = (bf16_t)hv[j];
          }
          // re-zero acc for next chunk
#pragma unroll
          for (int nn = 0; nn < 4; ++nn) acc[mi][nn] = (f32x4){0.f, 0.f, 0.f, 0.f};
        }
      }
    }
    __syncthreads();   // all LDS reads of step s complete
    if (s < 63) {
      // write h(s) back into the LDS A-buffer (k = 64 + u region)
#pragma unroll
      for (int ch = 0; ch < 4; ++ch) {
        const int u = (ch * 8 + w) * 16 + lr;
        const int sl = 8 + (u >> 3);
        const int eb = (u & 7) * 2;
#pragma unroll
        for (int mi = 0; mi < 4; ++mi)
#pragma unroll
          for (int p = 0; p < 2; ++p) {
            const unsigned v = hpk[ch][mi * 2 + p];
            const int r0 = mi * 16 + lq * 4 + p * 2;
            *reinterpret_cast<uint16_t*>(smem + r0 * kRowB + ((sl ^ (r0 & 7)) * 16) + eb) =
                (uint16_t)v;
            const int r1 = r0 + 1;
            *reinterpret_cast<uint16_t*>(smem + r1 * kRowB + ((sl ^ (r1 & 7)) * 16) + eb) =
                (uint16_t)(v >> 16);
          }
      }
      // stage x(s+1)
      const int xr = t >> 3, xs_ = t & 7;
      const int offn = ((cell & 1) ? (63 - (s + 1)) : (s + 1)) * 64;
      bfrag xv = *reinterpret_cast<const bfrag*>(
          xsrc + (size_t)(row0 + xr) * kFS + offn + xs_ * 8);
      *reinterpret_cast<bfrag*>(smem + xr * kRowB + ((xs_ ^ (xr & 7)) * 16)) = xv;
    }
    __syncthreads();   // LDS ready for step s+1
  }
}

// ---------------- head: wave shuffle reduce ----------------

__global__ __launch_bounds__(256) void head_kernel(const bf16_t* __restrict__ hfin,
                                                   const float* __restrict__ W3,
                                                   const float* __restrict__ b3,
                                                   float* __restrict__ out) {
  const int b = blockIdx.x, t = threadIdx.x;
  const int l = t & 63, w = t >> 6;
  float acc[10];
#pragma unroll
  for (int j = 0; j < 10; ++j) acc[j] = 0.f;
  for (int k = t; k < 2048; k += 256) {
    const int cell = k >> 9, u = k & 511;
    const float hv = (float)hfin[((size_t)cell * kB + b) * kH + u];
#pragma unroll
    for (int j = 0; j < 10; ++j) acc[j] += hv * W3[j * 2048 + k];
  }
#pragma unroll
  for (int j = 0; j < 10; ++j)
#pragma unroll
    for (int o = 32; o > 0; o >>= 1) acc[j] += __shfl_down(acc[j], o, 64);
  __shared__ float wred[4][10];
  if (l == 0)
#pragma unroll
    for (int j = 0; j < 10; ++j) wred[w][j] = acc[j];
  __syncthreads();
  if (t == 0) {
    float logits[10];
#pragma unroll
    for (int j = 0; j < 10; ++j)
      logits[j] = wred[0][j] + wred[1][j] + wred[2][j] + wred[3][j] + b3[j];
    float mx = logits[0];
#pragma unroll
    for (int j = 1; j < 10; ++j) mx = fmaxf(mx, logits[j]);
    float se = 0.f;
#pragma unroll
    for (int j = 0; j < 10; ++j) se += expf(logits[j] - mx);
    const float lse = mx + logf(se);
#pragma unroll
    for (int j = 0; j < 10; ++j) out[(size_t)b * 10 + j] = logits[j] - lse;
  }
}

}  // namespace

extern "C" void kernel_launch(void* const* d_in, const int* in_sizes, int n_in,
                              void* d_out, int out_size, void* d_ws, size_t ws_size,
                              hipStream_t stream) {
  const float* x     = (const float*)d_in[0];
  const float* h0    = (const float*)d_in[1];
  const float* c0    = (const float*)d_in[2];
  const float* W1    = (const float*)d_in[3];
  const float* b1    = (const float*)d_in[4];
  const float* Wih_l = (const float*)d_in[5];
  const float* Whh_l = (const float*)d_in[6];
  const float* bih_l = (const float*)d_in[7];
  const float* bhh_l = (const float*)d_in[8];
  const float* Wih_r = (const float*)d_in[9];
  const float* Whh_r = (const float*)d_in[10];
  const float* bih_r = (const float*)d_in[11];
  const float* bhh_r = (const float*)d_in[12];
  const float* Wih_d = (const float*)d_in[13];
  const float* Whh_d = (const float*)d_in[14];
  const float* bih_d = (const float*)d_in[15];
  const float* bhh_d = (const float*)d_in[16];
  const float* W3    = (const float*)d_in[17];
  const float* b3    = (const float*)d_in[18];
  float* out = (float*)d_out;

  char* p = (char*)d_ws;
  auto take = [&](size_t bytes) {
    char* r = p;
    p += (bytes + 255) & ~(size_t)255;
    return r;
  };
  bf16_t* xb    = (bf16_t*)take((size_t)kB * kIN * 2);   // later reused as featT
  bf16_t* w1b   = (bf16_t*)take((size_t)kFS * kIN * 2);  // later reused as hfin
  bf16_t* feat  = (bf16_t*)take((size_t)kB * kFS * 2);
  bf16_t* wcat2 = (bf16_t*)take((size_t)3 * 128 * 9 * 2 * 64 * 8 * 2);
  float*  biasc = (float*)take((size_t)3 * kNG * 4);
  float*  cbuf  = (float*)take((size_t)4 * kB * kH * 4);
  bf16_t* featT = xb;   // safe: gemm_feat (reads xb) precedes transpose (writes featT)
  bf16_t* hfin  = w1b;  // safe: gemm_feat (reads w1b) precedes lstm_all

  (void)hipFuncSetAttribute(reinterpret_cast<const void*>(&lstm_all_kernel),
                            hipFuncAttributeMaxDynamicSharedMemorySize, 64 * kRowB);

  f2b4_kernel<<<(kB * kIN / 4) / 256, 256, 0, stream>>>(x, xb, kB * kIN / 4);
  f2b4_kernel<<<(kFS * kIN / 4) / 256, 256, 0, stream>>>(W1, w1b, kFS * kIN / 4);
  gemm_feat_kernel<<<dim3(1024), 256, 0, stream>>>(xb, w1b, b1, feat);
  transpose64_kernel<<<kB, 256, 0, stream>>>(feat, featT);
  {
    const int total = 3 * 128 * 9 * 2 * 64 * 8;
    pack_wcat2_kernel<<<(total + 255) / 256, 256, 0, stream>>>(
        Wih_l, Whh_l, Wih_r, Whh_r, Wih_d, Whh_d, wcat2);
  }
  pack_bias_kernel<<<(3 * kNG + 255) / 256, 256, 0, stream>>>(
      bih_l, bhh_l, bih_r, bhh_r, bih_d, bhh_d, biasc);

  lstm_all_kernel<<<dim3(256), 512, 64 * kRowB, stream>>>(
      feat, featT, wcat2, biasc, h0, c0, cbuf, hfin);

  head_kernel<<<kB, 256, 0, stream>>>(hfin, W3, b3, out);
}

// Round 11
// 4128.980 us; speedup vs baseline: 3.3411x; 3.3411x over previous
//
#include <hip/hip_runtime.h>
#include <cstddef>
#include <cstdint>

namespace {

constexpr int kB  = 4096;   // batch
constexpr int kIN = 4096;
constexpr int kFS = 4096;
constexpr int kS  = 64;
constexpr int kH  = 512;
constexpr int kNG = 2048;   // 4*H
constexpr int kKC = 576;    // 64 (input slice) + 512 (hidden)

typedef __bf16 bf16_t;
typedef __bf16 bfrag  __attribute__((ext_vector_type(8)));
typedef __bf16 bf16v4 __attribute__((ext_vector_type(4)));
typedef float  f32x4  __attribute__((ext_vector_type(4)));

__device__ __forceinline__ void gload16(const void* g, void* l) {
  __builtin_amdgcn_global_load_lds(
      (const __attribute__((address_space(1))) void*)g,
      (__attribute__((address_space(3))) void*)l, 16, 0, 0);
}

__device__ __forceinline__ float sigf(float x) { return 1.0f / (1.0f + __expf(-x)); }
__device__ __forceinline__ float tanh_fast(float x) {
  float e = __expf(2.0f * x);
  return 1.0f - 2.0f / (e + 1.0f);
}
__device__ __forceinline__ f32x4 mfma16(bfrag a, bfrag b, f32x4 c) {
  return __builtin_amdgcn_mfma_f32_16x16x32_bf16(a, b, c, 0, 0, 0);
}

// ---------------- pack kernels ----------------

__global__ __launch_bounds__(256) void f2b4_kernel(const float* __restrict__ in,
                                                   bf16_t* __restrict__ out, int n4) {
  int i = blockIdx.x * 256 + threadIdx.x;
  if (i >= n4) return;
  float4 v = reinterpret_cast<const float4*>(in)[i];
  bf16v4 o = {(bf16_t)v.x, (bf16_t)v.y, (bf16_t)v.z, (bf16_t)v.w};
  *reinterpret_cast<bf16v4*>(out + (size_t)i * 4) = o;
}

// wcat2: MFMA-fragment-order weight pack (verified R9).
// chunk (mat, nb, kt, kk) = 64 lanes x 8 bf16; lane l: col = nb*16+(l&15),
// k = kt*64 + kk*32 + (l>>4)*8. col c -> gate=(c>>4)&3, unit=(c>>6)*16+(c&15).
__global__ __launch_bounds__(256) void pack_wcat2_kernel(
    const float* __restrict__ Wih_l, const float* __restrict__ Whh_l,
    const float* __restrict__ Wih_r, const float* __restrict__ Whh_r,
    const float* __restrict__ Wih_d, const float* __restrict__ Whh_d,
    bf16_t* __restrict__ wcat2) {
  const int total = 3 * 128 * 9 * 2 * 64 * 8;
  int idx = blockIdx.x * 256 + threadIdx.x;
  if (idx >= total) return;
  int e  = idx & 7;
  int l  = (idx >> 3) & 63;
  int kk = (idx >> 9) & 1;
  int r  = idx >> 10;
  int kt = r % 9;
  int matnb = r / 9;
  int mat = matnb >> 7;
  int nb  = matnb & 127;
  const int c = nb * 16 + (l & 15);
  const int g = (c >> 4) & 3;
  const int u = (c >> 6) * 16 + (c & 15);
  const int orow = g * kH + u;
  const int k = kt * 64 + kk * 32 + (l >> 4) * 8 + e;
  const float* Wih = (mat == 0) ? Wih_l : (mat == 1) ? Wih_r : Wih_d;
  const float* Whh = (mat == 0) ? Whh_l : (mat == 1) ? Whh_r : Whh_d;
  float v = (k < 64) ? Wih[(size_t)orow * 64 + k] : Whh[(size_t)orow * 512 + (k - 64)];
  wcat2[idx] = (bf16_t)v;
}

__global__ __launch_bounds__(256) void pack_bias_kernel(
    const float* __restrict__ bih_l, const float* __restrict__ bhh_l,
    const float* __restrict__ bih_r, const float* __restrict__ bhh_r,
    const float* __restrict__ bih_d, const float* __restrict__ bhh_d,
    float* __restrict__ biasc) {
  int idx = blockIdx.x * 256 + threadIdx.x;
  if (idx >= 3 * kNG) return;
  int mat = idx / kNG;
  int c = idx - mat * kNG;
  int g = (c >> 4) & 3;
  int u = (c >> 6) * 16 + (c & 15);
  int orow = g * kH + u;
  const float* bi = (mat == 0) ? bih_l : (mat == 1) ? bih_r : bih_d;
  const float* bh = (mat == 0) ? bhh_l : (mat == 1) ? bhh_r : bhh_d;
  biasc[idx] = bi[orow] + bh[orow];
}

__global__ __launch_bounds__(256) void pack_hc_kernel(const float* __restrict__ h0,
                                                      const float* __restrict__ c0,
                                                      bf16_t* __restrict__ hbuf0,
                                                      float* __restrict__ cbuf, int n) {
  int i = blockIdx.x * 256 + threadIdx.x;
  if (i >= n) return;
  hbuf0[i] = (bf16_t)h0[i];
  cbuf[i]  = c0[i];
}

__global__ __launch_bounds__(256) void transpose64_kernel(const bf16_t* __restrict__ feat,
                                                          bf16_t* __restrict__ featT) {
  __shared__ bf16_t tile[64][65];
  const int b = blockIdx.x;
  const bf16_t* src = feat + (size_t)b * kFS;
  bf16_t* dst = featT + (size_t)b * kFS;
  for (int i = threadIdx.x; i < 4096; i += 256) tile[i >> 6][i & 63] = src[i];
  __syncthreads();
  for (int i = threadIdx.x; i < 4096; i += 256) dst[i] = tile[i & 63][i >> 6];
}

// ---------------- feat GEMM (unchanged, verified) ----------------

__global__ __launch_bounds__(256, 4) void gemm_feat_kernel(
    const bf16_t* __restrict__ X, const bf16_t* __restrict__ W,
    const float* __restrict__ b1, bf16_t* __restrict__ feat) {
  __shared__ bf16_t As[128 * 32];
  __shared__ bf16_t Bs[128 * 32];
  const int t = threadIdx.x;
  const int bid = blockIdx.x;
  const int widx = (bid & 7) * 128 + (bid >> 3);
  const int bm = widx & 31, bn = widx >> 5;
  const int w = t >> 6, l = t & 63;
  const int wm = (w >> 1) * 64, wn = (w & 1) * 64;
  const int sr = t >> 2;
  const int skS = ((t & 3) ^ ((t >> 3) & 3)) * 8;
  const int lr = l & 15;
  const int lkS = ((l >> 4) ^ ((l >> 1) & 3)) * 8;
  const int lrow4 = (l >> 4) * 4;

  f32x4 acc[4][4];
#pragma unroll
  for (int i = 0; i < 4; ++i)
#pragma unroll
    for (int j = 0; j < 4; ++j) acc[i][j] = (f32x4){0.f, 0.f, 0.f, 0.f};

  const bf16_t* ga = X + (size_t)(bm * 128 + sr) * kIN + skS;
  const bf16_t* gb = W + (size_t)(bn * 128 + sr) * kIN + skS;
  bf16_t* lA = As + w * 512;
  bf16_t* lB = Bs + w * 512;

  for (int kt = 0; kt < kIN / 32; ++kt) {
    gload16(ga, lA);
    gload16(ga + (size_t)64 * kIN, lA + 2048);
    gload16(gb, lB);
    gload16(gb + (size_t)64 * kIN, lB + 2048);
    ga += 32; gb += 32;
    __syncthreads();
    bfrag a[4], b[4];
#pragma unroll
    for (int mi = 0; mi < 4; ++mi)
      a[mi] = *reinterpret_cast<const bfrag*>(&As[(wm + mi * 16 + lr) * 32 + lkS]);
#pragma unroll
    for (int ni = 0; ni < 4; ++ni)
      b[ni] = *reinterpret_cast<const bfrag*>(&Bs[(wn + ni * 16 + lr) * 32 + lkS]);
#pragma unroll
    for (int mi = 0; mi < 4; ++mi)
#pragma unroll
      for (int ni = 0; ni < 4; ++ni)
        acc[mi][ni] = __builtin_amdgcn_mfma_f32_16x16x32_bf16(a[mi], b[ni], acc[mi][ni], 0, 0, 0);
    __syncthreads();
  }

#pragma unroll
  for (int ni = 0; ni < 4; ++ni) {
    const int col = bn * 128 + wn + ni * 16 + lr;
    const float bb = b1[col];
#pragma unroll
    for (int mi = 0; mi < 4; ++mi) {
#pragma unroll
      for (int r = 0; r < 4; ++r) {
        const int row = bm * 128 + wm + mi * 16 + lrow4 + r;
        float v = acc[mi][ni][r] + bb;
        feat[(size_t)row * kFS + col] = (bf16_t)fmaxf(v, 0.0f);
      }
    }
  }
}

// ---------------- step kernel: 128x128 tile, 4 waves (2Mx2N, wave 64x64) ----------------
// Occupancy-first rework of R9: acc = 64 VGPR (64x64 wave tile) -> target <=168 VGPR,
// 3 blocks/CU co-resident (12 waves/CU TLP hides b-load L2 latency, A-stage, epilogue).
// A via LDS (16 KB/tile, double-buffered, T2 swizzle). B fragments direct from wcat2
// (ping-pong regs, full unroll = static indices). Per tile: stage(kt+1) -> loadB(kt+1)
// (order pinned by sched_barrier) -> ds_read + MFMA -> vmcnt(8) (4 stage loads oldest;
// 8 tracked b-loads may stay in flight) -> barrier. Epilogue per-lane: gate=nn, unit
// in-lane since (bn*8+wcn*4) % 4 == 0.

__global__ __launch_bounds__(256, 3) void lstm_step_kernel(
    const bf16_t* __restrict__ feat, const bf16_t* __restrict__ featT,
    const bf16_t* __restrict__ wcat2, const float* __restrict__ biasc,
    const bf16_t* __restrict__ hin, bf16_t* __restrict__ hout,
    float* __restrict__ cbuf, int s) {
  extern __shared__ __align__(16) char smem[];   // 2 x 16 KB A buffers

  const int t = threadIdx.x;
  const int l = t & 63, w = t >> 6;        // 4 waves
  const int wr = w >> 1, wcn = w & 1;      // 2M x 2N; wave tile 64x64
  const int lr = l & 15, lq = l >> 4;
  const int sx = lr & 7;
  const int srow = l >> 3;
  const int sslot = (l & 7) ^ srow;        // pre-swizzled global 16B-slot

  // grid 2048 = 4 cell x 32 bm x 16 bn; XCD swizzle (bijective, 2048 % 8 == 0).
  // Per XCD: 256 consecutive widx = half of one cell -> B footprint 2.36 MB (L2-fit),
  // each bn panel shared by 16 bm blocks.
  const int bid = blockIdx.x;
  const int widx = (bid & 7) * 256 + (bid >> 3);
  const int cell = widx >> 9;
  const int rwk = widx & 511;
  const int bm = rwk >> 4, bn = rwk & 15;

  const bf16_t* xsrc = (cell < 2) ? feat : featT;
  const int off = ((cell & 1) ? (63 - s) : s) * 64;
  const int mat = (cell < 2) ? cell : 2;
  const bf16_t* hc = hin + (size_t)cell * kB * kH;

  // A staging: 128 rows x 64 K per tile; 256 threads x 4 loads.
  auto stageA = [&](int kt, int buf) {
    bf16_t* base = (bf16_t*)(smem + buf * 16384);
#pragma unroll
    for (int j = 0; j < 4; ++j) {
      const int row0 = j * 32 + w * 8;          // wave-uniform
      bf16_t* dst = base + row0 * 64;
      const bf16_t* src = (kt == 0)
          ? xsrc + (size_t)(bm * 128 + row0 + srow) * kFS + off + sslot * 8
          : hc + (size_t)(bm * 128 + row0 + srow) * kH + (kt - 1) * 64 + sslot * 8;
      gload16(src, dst);
    }
  };

  // B fragments: wave covers nb = bn*8 + wcn*4 + nn (nn=0..3) -> 64 cols.
  const size_t nbB = (size_t)mat * 128 + bn * 8 + wcn * 4;
  auto loadB = [&](int kt, bfrag (&d)[8]) {
#pragma unroll
    for (int nn = 0; nn < 4; ++nn)
#pragma unroll
      for (int kk = 0; kk < 2; ++kk)
        d[nn * 2 + kk] = *reinterpret_cast<const bfrag*>(
            wcat2 + ((((nbB + nn) * 9 + kt) * 2 + kk) << 9) + l * 8);
  };

  f32x4 acc[4][4];
#pragma unroll
  for (int i = 0; i < 4; ++i)
#pragma unroll
    for (int j = 0; j < 4; ++j) acc[i][j] = (f32x4){0.f, 0.f, 0.f, 0.f};

  bfrag bE[8], bO[8];

  // prologue
  stageA(0, 0);
  loadB(0, bE);
  asm volatile("s_waitcnt vmcnt(0)" ::: "memory");
  __builtin_amdgcn_sched_barrier(0);
  __builtin_amdgcn_s_barrier();

#pragma unroll
  for (int kt = 0; kt < 9; ++kt) {
    const int cur = kt & 1;
    if (kt < 8) {
      stageA(kt + 1, cur ^ 1);
      __builtin_amdgcn_sched_barrier(0);   // pin issue order: stage (oldest) then b
      if (kt & 1) loadB(kt + 1, bE); else loadB(kt + 1, bO);
      __builtin_amdgcn_sched_barrier(0);   // keep b-loads issued before the MFMA region
    }
    const bf16_t* As_ = (const bf16_t*)(smem + cur * 16384);
#pragma unroll
    for (int kk = 0; kk < 2; ++kk) {
      bfrag a[4];
#pragma unroll
      for (int mi = 0; mi < 4; ++mi)
        a[mi] = *reinterpret_cast<const bfrag*>(
            As_ + (wr * 64 + mi * 16 + lr) * 64 + (((kk * 4 + lq) ^ sx) * 8));
      __builtin_amdgcn_s_setprio(1);
#pragma unroll
      for (int mi = 0; mi < 4; ++mi)
#pragma unroll
        for (int nn = 0; nn < 4; ++nn)
          acc[mi][nn] = (kt & 1) ? mfma16(a[mi], bO[nn * 2 + kk], acc[mi][nn])
                                 : mfma16(a[mi], bE[nn * 2 + kk], acc[mi][nn]);
      __builtin_amdgcn_s_setprio(0);
    }
    __builtin_amdgcn_sched_barrier(0);
    if (kt < 8) {
      asm volatile("s_waitcnt vmcnt(8)" ::: "memory");  // stage(kt+1) landed
      __builtin_amdgcn_sched_barrier(0);
      __builtin_amdgcn_s_barrier();
    }
  }

  // ---- epilogue: pure per-lane gate fusion (no LDS, no barriers) ----
  const int nb0 = bn * 8 + wcn * 4;
  const float* bbp = biasc + mat * kNG + nb0 * 16;
  const float bb0 = bbp[lr];
  const float bb1 = bbp[16 + lr];
  const float bb2 = bbp[32 + lr];
  const float bb3 = bbp[48 + lr];
  const int u = (bn * 2 + wcn) * 16 + lr;
  const int row0g = bm * 128 + wr * 64 + lq * 4;
#pragma unroll
  for (int mi = 0; mi < 4; ++mi) {
#pragma unroll
    for (int j = 0; j < 4; ++j) {
      const float iv = sigf(acc[mi][0][j] + bb0);
      const float fv = sigf(acc[mi][1][j] + bb1);
      const float gv = tanh_fast(acc[mi][2][j] + bb2);
      const float ov = sigf(acc[mi][3][j] + bb3);
      const int row = row0g + mi * 16 + j;
      const size_t cidx = ((size_t)cell * kB + row) * kH + u;
      const float cn = fv * cbuf[cidx] + iv * gv;
      cbuf[cidx] = cn;
      hout[cidx] = (bf16_t)(ov * tanh_fast(cn));
    }
  }
}

// ---------------- head: wave shuffle reduce ----------------

__global__ __launch_bounds__(256) void head_kernel(const bf16_t* __restrict__ hfin,
                                                   const float* __restrict__ W3,
                                                   const float* __restrict__ b3,
                                                   float* __restrict__ out) {
  const int b = blockIdx.x, t = threadIdx.x;
  const int l = t & 63, w = t >> 6;
  float acc[10];
#pragma unroll
  for (int j = 0; j < 10; ++j) acc[j] = 0.f;
  for (int k = t; k < 2048; k += 256) {
    const int cell = k >> 9, u = k & 511;
    const float hv = (float)hfin[((size_t)cell * kB + b) * kH + u];
#pragma unroll
    for (int j = 0; j < 10; ++j) acc[j] += hv * W3[j * 2048 + k];
  }
#pragma unroll
  for (int j = 0; j < 10; ++j)
#pragma unroll
    for (int o = 32; o > 0; o >>= 1) acc[j] += __shfl_down(acc[j], o, 64);
  __shared__ float wred[4][10];
  if (l == 0)
#pragma unroll
    for (int j = 0; j < 10; ++j) wred[w][j] = acc[j];
  __syncthreads();
  if (t == 0) {
    float logits[10];
#pragma unroll
    for (int j = 0; j < 10; ++j)
      logits[j] = wred[0][j] + wred[1][j] + wred[2][j] + wred[3][j] + b3[j];
    float mx = logits[0];
#pragma unroll
    for (int j = 1; j < 10; ++j) mx = fmaxf(mx, logits[j]);
    float se = 0.f;
#pragma unroll
    for (int j = 0; j < 10; ++j) se += expf(logits[j] - mx);
    const float lse = mx + logf(se);
#pragma unroll
    for (int j = 0; j < 10; ++j) out[(size_t)b * 10 + j] = logits[j] - lse;
  }
}

}  // namespace

extern "C" void kernel_launch(void* const* d_in, const int* in_sizes, int n_in,
                              void* d_out, int out_size, void* d_ws, size_t ws_size,
                              hipStream_t stream) {
  const float* x     = (const float*)d_in[0];
  const float* h0    = (const float*)d_in[1];
  const float* c0    = (const float*)d_in[2];
  const float* W1    = (const float*)d_in[3];
  const float* b1    = (const float*)d_in[4];
  const float* Wih_l = (const float*)d_in[5];
  const float* Whh_l = (const float*)d_in[6];
  const float* bih_l = (const float*)d_in[7];
  const float* bhh_l = (const float*)d_in[8];
  const float* Wih_r = (const float*)d_in[9];
  const float* Whh_r = (const float*)d_in[10];
  const float* bih_r = (const float*)d_in[11];
  const float* bhh_r = (const float*)d_in[12];
  const float* Wih_d = (const float*)d_in[13];
  const float* Whh_d = (const float*)d_in[14];
  const float* bih_d = (const float*)d_in[15];
  const float* bhh_d = (const float*)d_in[16];
  const float* W3    = (const float*)d_in[17];
  const float* b3    = (const float*)d_in[18];
  float* out = (float*)d_out;

  char* p = (char*)d_ws;
  auto take = [&](size_t bytes) {
    char* r = p;
    p += (bytes + 255) & ~(size_t)255;
    return r;
  };
  bf16_t* xb    = (bf16_t*)take((size_t)kB * kIN * 2);   // later reused as featT
  bf16_t* w1b   = (bf16_t*)take((size_t)kFS * kIN * 2);  // later reused as hbuf (2 slots)
  bf16_t* feat  = (bf16_t*)take((size_t)kB * kFS * 2);
  bf16_t* wcat2 = (bf16_t*)take((size_t)3 * 128 * 9 * 2 * 64 * 8 * 2);
  float*  biasc = (float*)take((size_t)3 * kNG * 4);
  float*  cbuf  = (float*)take((size_t)4 * kB * kH * 4);
  bf16_t* featT = xb;   // safe: gemm_feat (reads xb) precedes transpose (writes featT)
  bf16_t* hbuf  = w1b;  // safe: gemm_feat (reads w1b) precedes pack_hc
  const size_t HSZ = (size_t)4 * kB * kH;

  (void)hipFuncSetAttribute(reinterpret_cast<const void*>(&lstm_step_kernel),
                            hipFuncAttributeMaxDynamicSharedMemorySize, 32768);

  f2b4_kernel<<<(kB * kIN / 4) / 256, 256, 0, stream>>>(x, xb, kB * kIN / 4);
  f2b4_kernel<<<(kFS * kIN / 4) / 256, 256, 0, stream>>>(W1, w1b, kFS * kIN / 4);
  gemm_feat_kernel<<<dim3(1024), 256, 0, stream>>>(xb, w1b, b1, feat);
  transpose64_kernel<<<kB, 256, 0, stream>>>(feat, featT);
  {
    const int total = 3 * 128 * 9 * 2 * 64 * 8;
    pack_wcat2_kernel<<<(total + 255) / 256, 256, 0, stream>>>(
        Wih_l, Whh_l, Wih_r, Whh_r, Wih_d, Whh_d, wcat2);
  }
  pack_bias_kernel<<<(3 * kNG + 255) / 256, 256, 0, stream>>>(
      bih_l, bhh_l, bih_r, bhh_r, bih_d, bhh_d, biasc);
  pack_hc_kernel<<<(int)(HSZ / 256), 256, 0, stream>>>(h0, c0, hbuf, cbuf, (int)HSZ);

  for (int s = 0; s < 64; ++s) {
    lstm_step_kernel<<<dim3(2048), 256, 32768, stream>>>(
        feat, featT, wcat2, biasc,
        hbuf + (size_t)(s & 1) * HSZ, hbuf + (size_t)((s + 1) & 1) * HSZ, cbuf, s);
  }
  head_kernel<<<kB, 256, 0, stream>>>(hbuf, W3, b3, out);
}

// Round 12
// 3951.879 us; speedup vs baseline: 3.4908x; 1.0448x over previous
//
#include <hip/hip_runtime.h>
#include <cstddef>
#include <cstdint>

namespace {

constexpr int kB  = 4096;   // batch
constexpr int kIN = 4096;
constexpr int kFS = 4096;
constexpr int kS  = 64;
constexpr int kH  = 512;
constexpr int kNG = 2048;   // 4*H
constexpr int kKC = 576;    // 64 (input slice) + 512 (hidden)

typedef __bf16 bf16_t;
typedef __bf16 bfrag  __attribute__((ext_vector_type(8)));
typedef __bf16 bf16v4 __attribute__((ext_vector_type(4)));
typedef float  f32x4  __attribute__((ext_vector_type(4)));

__device__ __forceinline__ void gload16(const void* g, void* l) {
  __builtin_amdgcn_global_load_lds(
      (const __attribute__((address_space(1))) void*)g,
      (__attribute__((address_space(3))) void*)l, 16, 0, 0);
}

__device__ __forceinline__ float sigf(float x) { return 1.0f / (1.0f + __expf(-x)); }
__device__ __forceinline__ float tanh_fast(float x) {
  float e = __expf(2.0f * x);
  return 1.0f - 2.0f / (e + 1.0f);
}

__device__ __forceinline__ f32x4 mfma16(bfrag a, bfrag b, f32x4 c) {
  return __builtin_amdgcn_mfma_f32_16x16x32_bf16(a, b, c, 0, 0, 0);
}

// ---------------- pack kernels ----------------

__global__ __launch_bounds__(256) void f2b4_kernel(const float* __restrict__ in,
                                                   bf16_t* __restrict__ out, int n4) {
  int i = blockIdx.x * 256 + threadIdx.x;
  if (i >= n4) return;
  float4 v = reinterpret_cast<const float4*>(in)[i];
  bf16v4 o = {(bf16_t)v.x, (bf16_t)v.y, (bf16_t)v.z, (bf16_t)v.w};
  *reinterpret_cast<bf16v4*>(out + (size_t)i * 4) = o;
}

// wcat2: MFMA-fragment-order weight pack (verified R9).
// chunk (mat, nb, kt, kk) = 64 lanes x 8 bf16; lane l: col = nb*16+(l&15),
// k = kt*64 + kk*32 + (l>>4)*8. col c -> gate=(c>>4)&3, unit=(c>>6)*16+(c&15).
__global__ __launch_bounds__(256) void pack_wcat2_kernel(
    const float* __restrict__ Wih_l, const float* __restrict__ Whh_l,
    const float* __restrict__ Wih_r, const float* __restrict__ Whh_r,
    const float* __restrict__ Wih_d, const float* __restrict__ Whh_d,
    bf16_t* __restrict__ wcat2) {
  const int total = 3 * 128 * 9 * 2 * 64 * 8;
  int idx = blockIdx.x * 256 + threadIdx.x;
  if (idx >= total) return;
  int e  = idx & 7;
  int l  = (idx >> 3) & 63;
  int kk = (idx >> 9) & 1;
  int r  = idx >> 10;
  int kt = r % 9;
  int matnb = r / 9;
  int mat = matnb >> 7;
  int nb  = matnb & 127;
  const int c = nb * 16 + (l & 15);
  const int g = (c >> 4) & 3;
  const int u = (c >> 6) * 16 + (c & 15);
  const int orow = g * kH + u;
  const int k = kt * 64 + kk * 32 + (l >> 4) * 8 + e;
  const float* Wih = (mat == 0) ? Wih_l : (mat == 1) ? Wih_r : Wih_d;
  const float* Whh = (mat == 0) ? Whh_l : (mat == 1) ? Whh_r : Whh_d;
  float v = (k < 64) ? Wih[(size_t)orow * 64 + k] : Whh[(size_t)orow * 512 + (k - 64)];
  wcat2[idx] = (bf16_t)v;
}

__global__ __launch_bounds__(256) void pack_bias_kernel(
    const float* __restrict__ bih_l, const float* __restrict__ bhh_l,
    const float* __restrict__ bih_r, const float* __restrict__ bhh_r,
    const float* __restrict__ bih_d, const float* __restrict__ bhh_d,
    float* __restrict__ biasc) {
  int idx = blockIdx.x * 256 + threadIdx.x;
  if (idx >= 3 * kNG) return;
  int mat = idx / kNG;
  int c = idx - mat * kNG;
  int g = (c >> 4) & 3;
  int u = (c >> 6) * 16 + (c & 15);
  int orow = g * kH + u;
  const float* bi = (mat == 0) ? bih_l : (mat == 1) ? bih_r : bih_d;
  const float* bh = (mat == 0) ? bhh_l : (mat == 1) ? bhh_r : bhh_d;
  biasc[idx] = bi[orow] + bh[orow];
}

__global__ __launch_bounds__(256) void pack_hc_kernel(const float* __restrict__ h0,
                                                      const float* __restrict__ c0,
                                                      bf16_t* __restrict__ hbuf0,
                                                      float* __restrict__ cbuf, int n) {
  int i = blockIdx.x * 256 + threadIdx.x;
  if (i >= n) return;
  hbuf0[i] = (bf16_t)h0[i];
  __builtin_nontemporal_store(c0[i], &cbuf[i]);   // keep c out of L2 from the start
}

__global__ __launch_bounds__(256) void transpose64_kernel(const bf16_t* __restrict__ feat,
                                                          bf16_t* __restrict__ featT) {
  __shared__ bf16_t tile[64][65];
  const int b = blockIdx.x;
  const bf16_t* src = feat + (size_t)b * kFS;
  bf16_t* dst = featT + (size_t)b * kFS;
  for (int i = threadIdx.x; i < 4096; i += 256) tile[i >> 6][i & 63] = src[i];
  __syncthreads();
  for (int i = threadIdx.x; i < 4096; i += 256) dst[i] = tile[i & 63][i >> 6];
}

// ---------------- feat GEMM (unchanged, verified) ----------------

__global__ __launch_bounds__(256, 4) void gemm_feat_kernel(
    const bf16_t* __restrict__ X, const bf16_t* __restrict__ W,
    const float* __restrict__ b1, bf16_t* __restrict__ feat) {
  __shared__ bf16_t As[128 * 32];
  __shared__ bf16_t Bs[128 * 32];
  const int t = threadIdx.x;
  const int bid = blockIdx.x;
  const int widx = (bid & 7) * 128 + (bid >> 3);
  const int bm = widx & 31, bn = widx >> 5;
  const int w = t >> 6, l = t & 63;
  const int wm = (w >> 1) * 64, wn = (w & 1) * 64;
  const int sr = t >> 2;
  const int skS = ((t & 3) ^ ((t >> 3) & 3)) * 8;
  const int lr = l & 15;
  const int lkS = ((l >> 4) ^ ((l >> 1) & 3)) * 8;
  const int lrow4 = (l >> 4) * 4;

  f32x4 acc[4][4];
#pragma unroll
  for (int i = 0; i < 4; ++i)
#pragma unroll
    for (int j = 0; j < 4; ++j) acc[i][j] = (f32x4){0.f, 0.f, 0.f, 0.f};

  const bf16_t* ga = X + (size_t)(bm * 128 + sr) * kIN + skS;
  const bf16_t* gb = W + (size_t)(bn * 128 + sr) * kIN + skS;
  bf16_t* lA = As + w * 512;
  bf16_t* lB = Bs + w * 512;

  for (int kt = 0; kt < kIN / 32; ++kt) {
    gload16(ga, lA);
    gload16(ga + (size_t)64 * kIN, lA + 2048);
    gload16(gb, lB);
    gload16(gb + (size_t)64 * kIN, lB + 2048);
    ga += 32; gb += 32;
    __syncthreads();
    bfrag a[4], b[4];
#pragma unroll
    for (int mi = 0; mi < 4; ++mi)
      a[mi] = *reinterpret_cast<const bfrag*>(&As[(wm + mi * 16 + lr) * 32 + lkS]);
#pragma unroll
    for (int ni = 0; ni < 4; ++ni)
      b[ni] = *reinterpret_cast<const bfrag*>(&Bs[(wn + ni * 16 + lr) * 32 + lkS]);
#pragma unroll
    for (int mi = 0; mi < 4; ++mi)
#pragma unroll
      for (int ni = 0; ni < 4; ++ni)
        acc[mi][ni] = __builtin_amdgcn_mfma_f32_16x16x32_bf16(a[mi], b[ni], acc[mi][ni], 0, 0, 0);
    __syncthreads();
  }

#pragma unroll
  for (int ni = 0; ni < 4; ++ni) {
    const int col = bn * 128 + wn + ni * 16 + lr;
    const float bb = b1[col];
#pragma unroll
    for (int mi = 0; mi < 4; ++mi) {
#pragma unroll
      for (int r = 0; r < 4; ++r) {
        const int row = bm * 128 + wm + mi * 16 + lrow4 + r;
        float v = acc[mi][ni][r] + bb;
        feat[(size_t)row * kFS + col] = (bf16_t)fmaxf(v, 0.0f);
      }
    }
  }
}

// ---------------- step kernel: R9 structure + non-temporal c ----------------
// 256x256 tile, 8 waves (2Mx4N, wave 128x64). A via LDS (32 KB dbuf, T2 swizzle);
// B fragments direct from fragment-ordered wcat2 (ping-pong regs, full unroll).
// XCD grouping: consecutive widx = all 8 bn of one (cell,bm) -> h written and re-read
// by the same XCD across steps. c (zero-reuse stream) uses nontemporal load/store so
// it does NOT evict the weight/h/x working set from L2 — the single change vs R9.

__global__ __launch_bounds__(512, 1) void lstm_step_kernel(
    const bf16_t* __restrict__ feat, const bf16_t* __restrict__ featT,
    const bf16_t* __restrict__ wcat2, const float* __restrict__ biasc,
    const bf16_t* __restrict__ hin, bf16_t* __restrict__ hout,
    float* __restrict__ cbuf, int s) {
  extern __shared__ __align__(16) char smem[];   // 2 x 32 KB A buffers

  const int t = threadIdx.x;
  const int l = t & 63, w = t >> 6;
  const int wr = w >> 2, wc = w & 3;   // 2M x 4N; wave tile 128 x 64
  const int lr = l & 15, lq = l >> 4;
  const int sx = lr & 7;
  const int srow = l >> 3;
  const int sslot = (l & 7) ^ (srow & 7);

  // grid 512 = 4 cell x 16 bm x 8 bn; XCD swizzle (bijective, 512 % 8 == 0)
  const int bid = blockIdx.x;
  const int widx = (bid & 7) * 64 + (bid >> 3);
  const int cell = widx >> 7;
  const int rwk = widx & 127;
  const int bm = rwk >> 3, bn = rwk & 7;

  const bf16_t* xsrc = (cell < 2) ? feat : featT;
  const int off = ((cell & 1) ? (63 - s) : s) * 64;
  const int mat = (cell < 2) ? cell : 2;
  const bf16_t* hc = hin + (size_t)cell * kB * kH;

  // A staging: 256 rows x 64 K per tile; 512 threads x 4 loads.
  auto stageA = [&](int kt, int buf) {
    bf16_t* base = (bf16_t*)(smem + buf * 32768);
#pragma unroll
    for (int j = 0; j < 4; ++j) {
      const int row0 = j * 64 + w * 8;          // wave-uniform
      bf16_t* dst = base + row0 * 64;
      const bf16_t* src = (kt == 0)
          ? xsrc + (size_t)(bm * 256 + row0 + srow) * kFS + off + sslot * 8
          : hc + (size_t)(bm * 256 + row0 + srow) * kH + (kt - 1) * 64 + sslot * 8;
      gload16(src, dst);
    }
  };

  // B fragment loads: chunk (mat, nb, kt, kk) at elem offset chunkIdx*512 + l*8.
  const size_t wb0 = ((size_t)mat * 128 + bn * 16 + wc * 4) * 9;   // chunk row for nn=0
  auto loadB = [&](int kt, bfrag (&d)[8]) {
#pragma unroll
    for (int nn = 0; nn < 4; ++nn)
#pragma unroll
      for (int kk = 0; kk < 2; ++kk)
        d[nn * 2 + kk] = *reinterpret_cast<const bfrag*>(
            wcat2 + (((wb0 + (size_t)nn * 9 + kt) * 2 + kk) << 9) + l * 8);
  };

  f32x4 acc[8][4];
#pragma unroll
  for (int i = 0; i < 8; ++i)
#pragma unroll
    for (int j = 0; j < 4; ++j) acc[i][j] = (f32x4){0.f, 0.f, 0.f, 0.f};

  bfrag bA[8], bB[8];

  // prologue
  stageA(0, 0);
  loadB(0, bA);
  asm volatile("s_waitcnt vmcnt(0)" ::: "memory");
  __builtin_amdgcn_sched_barrier(0);
  __builtin_amdgcn_s_barrier();

#pragma unroll
  for (int kt = 0; kt < 9; ++kt) {
    const int cur = kt & 1;
    const bf16_t* As_ = (const bf16_t*)(smem + cur * 32768);
    bfrag (&bCur)[8] = (kt & 1) ? bB : bA;
    bfrag (&bNxt)[8] = (kt & 1) ? bA : bB;

    if (kt < 8) stageA(kt + 1, cur ^ 1);

    bfrag a[8];
    // ---- sub-burst 1: mi 0..3 ----
#pragma unroll
    for (int mi = 0; mi < 4; ++mi)
#pragma unroll
      for (int kk = 0; kk < 2; ++kk)
        a[mi * 2 + kk] = *reinterpret_cast<const bfrag*>(
            As_ + (wr * 128 + mi * 16 + lr) * 64 + (((kk * 4 + lq) ^ sx) * 8));
    __builtin_amdgcn_s_setprio(1);
#pragma unroll
    for (int kk = 0; kk < 2; ++kk)
#pragma unroll
      for (int mi = 0; mi < 4; ++mi)
#pragma unroll
        for (int nn = 0; nn < 4; ++nn)
          acc[mi][nn] = mfma16(a[mi * 2 + kk], bCur[nn * 2 + kk], acc[mi][nn]);
    __builtin_amdgcn_s_setprio(0);

    if (kt < 8) loadB(kt + 1, bNxt);   // lands under sub-burst 2 + barrier

    // ---- sub-burst 2: mi 4..7 ----
#pragma unroll
    for (int mi = 0; mi < 4; ++mi)
#pragma unroll
      for (int kk = 0; kk < 2; ++kk)
        a[mi * 2 + kk] = *reinterpret_cast<const bfrag*>(
            As_ + (wr * 128 + 64 + mi * 16 + lr) * 64 + (((kk * 4 + lq) ^ sx) * 8));
    __builtin_amdgcn_s_setprio(1);
#pragma unroll
    for (int kk = 0; kk < 2; ++kk)
#pragma unroll
      for (int mi = 0; mi < 4; ++mi)
#pragma unroll
        for (int nn = 0; nn < 4; ++nn)
          acc[4 + mi][nn] = mfma16(a[mi * 2 + kk], bCur[nn * 2 + kk], acc[4 + mi][nn]);
    __builtin_amdgcn_s_setprio(0);
    __builtin_amdgcn_sched_barrier(0);

    if (kt < 8) {
      asm volatile("s_waitcnt vmcnt(8)" ::: "memory");  // A-stage landed; 8 b-loads in flight
      __builtin_amdgcn_sched_barrier(0);
      __builtin_amdgcn_s_barrier();
    }
  }

  // ---- epilogue: per-lane gate fusion; c via NON-TEMPORAL accesses ----
  const float* biasn = biasc + mat * kNG + bn * 256 + wc * 64;
  const float bb0 = biasn[0 * 16 + lr];
  const float bb1 = biasn[1 * 16 + lr];
  const float bb2 = biasn[2 * 16 + lr];
  const float bb3 = biasn[3 * 16 + lr];
  const int u = (bn * 4 + wc) * 16 + lr;
  const int row0 = bm * 256 + wr * 128 + lq * 4;
#pragma unroll
  for (int mi = 0; mi < 8; ++mi) {
#pragma unroll
    for (int j = 0; j < 4; ++j) {
      const float iv = sigf(acc[mi][0][j] + bb0);
      const float fv = sigf(acc[mi][1][j] + bb1);
      const float gv = tanh_fast(acc[mi][2][j] + bb2);
      const float ov = sigf(acc[mi][3][j] + bb3);
      const int row = row0 + mi * 16 + j;
      const size_t cidx = ((size_t)cell * kB + row) * kH + u;
      const float cold = __builtin_nontemporal_load(&cbuf[cidx]);
      const float cn = fv * cold + iv * gv;
      __builtin_nontemporal_store(cn, &cbuf[cidx]);
      hout[cidx] = (bf16_t)(ov * tanh_fast(cn));
    }
  }
}

// ---------------- head: wave shuffle reduce ----------------

__global__ __launch_bounds__(256) void head_kernel(const bf16_t* __restrict__ hfin,
                                                   const float* __restrict__ W3,
                                                   const float* __restrict__ b3,
                                                   float* __restrict__ out) {
  const int b = blockIdx.x, t = threadIdx.x;
  const int l = t & 63, w = t >> 6;
  float acc[10];
#pragma unroll
  for (int j = 0; j < 10; ++j) acc[j] = 0.f;
  for (int k = t; k < 2048; k += 256) {
    const int cell = k >> 9, u = k & 511;
    const float hv = (float)hfin[((size_t)cell * kB + b) * kH + u];
#pragma unroll
    for (int j = 0; j < 10; ++j) acc[j] += hv * W3[j * 2048 + k];
  }
#pragma unroll
  for (int j = 0; j < 10; ++j)
#pragma unroll
    for (int o = 32; o > 0; o >>= 1) acc[j] += __shfl_down(acc[j], o, 64);
  __shared__ float wred[4][10];
  if (l == 0)
#pragma unroll
    for (int j = 0; j < 10; ++j) wred[w][j] = acc[j];
  __syncthreads();
  if (t == 0) {
    float logits[10];
#pragma unroll
    for (int j = 0; j < 10; ++j)
      logits[j] = wred[0][j] + wred[1][j] + wred[2][j] + wred[3][j] + b3[j];
    float mx = logits[0];
#pragma unroll
    for (int j = 1; j < 10; ++j) mx = fmaxf(mx, logits[j]);
    float se = 0.f;
#pragma unroll
    for (int j = 0; j < 10; ++j) se += expf(logits[j] - mx);
    const float lse = mx + logf(se);
#pragma unroll
    for (int j = 0; j < 10; ++j) out[(size_t)b * 10 + j] = logits[j] - lse;
  }
}

}  // namespace

extern "C" void kernel_launch(void* const* d_in, const int* in_sizes, int n_in,
                              void* d_out, int out_size, void* d_ws, size_t ws_size,
                              hipStream_t stream) {
  const float* x     = (const float*)d_in[0];
  const float* h0    = (const float*)d_in[1];
  const float* c0    = (const float*)d_in[2];
  const float* W1    = (const float*)d_in[3];
  const float* b1    = (const float*)d_in[4];
  const float* Wih_l = (const float*)d_in[5];
  const float* Whh_l = (const float*)d_in[6];
  const float* bih_l = (const float*)d_in[7];
  const float* bhh_l = (const float*)d_in[8];
  const float* Wih_r = (const float*)d_in[9];
  const float* Whh_r = (const float*)d_in[10];
  const float* bih_r = (const float*)d_in[11];
  const float* bhh_r = (const float*)d_in[12];
  const float* Wih_d = (const float*)d_in[13];
  const float* Whh_d = (const float*)d_in[14];
  const float* bih_d = (const float*)d_in[15];
  const float* bhh_d = (const float*)d_in[16];
  const float* W3    = (const float*)d_in[17];
  const float* b3    = (const float*)d_in[18];
  float* out = (float*)d_out;

  char* p = (char*)d_ws;
  auto take = [&](size_t bytes) {
    char* r = p;
    p += (bytes + 255) & ~(size_t)255;
    return r;
  };
  bf16_t* xb    = (bf16_t*)take((size_t)kB * kIN * 2);   // later reused as featT
  bf16_t* w1b   = (bf16_t*)take((size_t)kFS * kIN * 2);  // later reused as hbuf (2 slots)
  bf16_t* feat  = (bf16_t*)take((size_t)kB * kFS * 2);
  bf16_t* wcat2 = (bf16_t*)take((size_t)3 * 128 * 9 * 2 * 64 * 8 * 2);
  float*  biasc = (float*)take((size_t)3 * kNG * 4);
  float*  cbuf  = (float*)take((size_t)4 * kB * kH * 4);
  bf16_t* featT = xb;   // safe: gemm_feat (reads xb) precedes transpose (writes featT)
  bf16_t* hbuf  = w1b;  // safe: gemm_feat (reads w1b) precedes pack_hc
  const size_t HSZ = (size_t)4 * kB * kH;

  (void)hipFuncSetAttribute(reinterpret_cast<const void*>(&lstm_step_kernel),
                            hipFuncAttributeMaxDynamicSharedMemorySize, 65536);

  f2b4_kernel<<<(kB * kIN / 4) / 256, 256, 0, stream>>>(x, xb, kB * kIN / 4);
  f2b4_kernel<<<(kFS * kIN / 4) / 256, 256, 0, stream>>>(W1, w1b, kFS * kIN / 4);
  gemm_feat_kernel<<<dim3(1024), 256, 0, stream>>>(xb, w1b, b1, feat);
  transpose64_kernel<<<kB, 256, 0, stream>>>(feat, featT);
  {
    const int total = 3 * 128 * 9 * 2 * 64 * 8;
    pack_wcat2_kernel<<<(total + 255) / 256, 256, 0, stream>>>(
        Wih_l, Whh_l, Wih_r, Whh_r, Wih_d, Whh_d, wcat2);
  }
  pack_bias_kernel<<<(3 * kNG + 255) / 256, 256, 0, stream>>>(
      bih_l, bhh_l, bih_r, bhh_r, bih_d, bhh_d, biasc);
  pack_hc_kernel<<<(int)(HSZ / 256), 256, 0, stream>>>(h0, c0, hbuf, cbuf, (int)HSZ);

  for (int s = 0; s < 64; ++s) {
    lstm_step_kernel<<<dim3(512), 512, 65536, stream>>>(
        feat, featT, wcat2, biasc,
        hbuf + (size_t)(s & 1) * HSZ, hbuf + (size_t)((s + 1) & 1) * HSZ, cbuf, s);
  }
  head_kernel<<<kB, 256, 0, stream>>>(hbuf, W3, b3, out);
}